// Round 1
// baseline (775.120 us; speedup 1.0000x reference)
//
#include <hip/hip_runtime.h>

typedef unsigned short u16;
typedef __attribute__((ext_vector_type(8))) _Float16 f16x8;
typedef __attribute__((ext_vector_type(4))) float f32x4;

#define S_CTX 2048
#define DMODEL 2048

#define WAITVM(N) asm volatile("s_waitcnt vmcnt(" #N ")" ::: "memory")
#define WAITLG0() asm volatile("s_waitcnt lgkmcnt(0)" ::: "memory")
#define SBAR() __builtin_amdgcn_s_barrier()
#define SCHED0() __builtin_amdgcn_sched_barrier(0)

#define MFMA_BLOCK(AF, BF)                                                    \
  _Pragma("unroll") for (int i_ = 0; i_ < 4; ++i_)                            \
      _Pragma("unroll") for (int n_ = 0; n_ < 4; ++n_)                        \
          acc[i_][n_] = __builtin_amdgcn_mfma_f32_16x16x32_f16(               \
              AF[i_], BF[n_], acc[i_][n_], 0, 0, 0);

__device__ __forceinline__ u16 f2h(float f) {
  _Float16 h = (_Float16)f; u16 u; __builtin_memcpy(&u, &h, 2); return u;
}
__device__ __forceinline__ float h2f(u16 u) {
  _Float16 h; __builtin_memcpy(&h, &u, 2); return (float)h;
}
__device__ __forceinline__ void gload16(const u16* g, u16* l) {
  __builtin_amdgcn_global_load_lds(
      (const __attribute__((address_space(1))) unsigned int*)g,
      (__attribute__((address_space(3))) unsigned int*)l, 16, 0, 0);
}

// One fused split pass. x -> fp16 pair (no scale). Wq,Wk -> fp16 pair (x64).
// Wv,Wo -> fp16 single (x64). Scales folded out downstream (q-prescale, /4096).
__global__ void split_all(const float* __restrict__ x, const float* __restrict__ Wq,
                          const float* __restrict__ Wk, const float* __restrict__ Wv,
                          const float* __restrict__ Wo,
                          u16* xh, u16* xl, u16* Wqh, u16* Wql,
                          u16* Wkh, u16* Wkl, u16* Wvh, u16* Woh) {
  size_t i = (size_t)blockIdx.x * 256 + threadIdx.x;
  const size_t NX = 8388608, NW = 4194304;
  if (i < NX) {
    float v = x[i];
    u16 h = f2h(v);
    xh[i] = h; xl[i] = f2h(v - h2f(h));
  } else {
    size_t j = i - NX;
    int wsel = (int)(j >> 22);
    size_t o = j & (NW - 1);
    if (wsel == 0) { float v = Wq[o] * 64.f; u16 h = f2h(v); Wqh[o] = h; Wql[o] = f2h(v - h2f(h)); }
    else if (wsel == 1) { float v = Wk[o] * 64.f; u16 h = f2h(v); Wkh[o] = h; Wkl[o] = f2h(v - h2f(h)); }
    else if (wsel == 2) { Wvh[o] = f2h(Wv[o] * 64.f); }
    else { Woh[o] = f2h(Wo[o] * 64.f); }
  }
}

// ---------------------------------------------------------------------------
// Pipelined 256x128-tile GEMM core (C = A * B^T), fp16 MFMA, 512 threads =
// 8 waves (4M x 2N), BK=32.  NT==3: AhBh+AhBl+AlBh (3 phases of 16 MFMA per
// K-tile); NT==1: AhBh only (1 phase).
//
// LDS: 4 half-buffers x 24 KiB = 96 KiB.  half = {A 256x32 (16 KiB) +
// B 128x32 (8 KiB)} in [k-quad][row][16B] layout -> fragment ds_read_b128 is
// bank-conflict-free (16 lanes read 256 contiguous bytes).  global_load_lds
// writes linearly (wave-uniform dst, lane-scattered SRC pre-permuted to match).
//
// Schedule per phase: {ds_read frags; issue 3 gload_lds; counted vmcnt;
// s_barrier; lgkmcnt(0); setprio(1); 16 MFMA; setprio(0); s_barrier}.
// Steady-state vmcnt oscillates 6->3: never drained to 0 (the m97 stall).
// Buffer-safety: every stage targets the buffer last read >=2 barriers ago.
//
// MODE 0: f32*oscale -> Cf ; MODE 1: fp16 pair -> (Ch,Cl) ; MODE 2: V^T -> Ch
// ---------------------------------------------------------------------------
template <int NT, int MODE>
__device__ __forceinline__ void gemm256(
    u16* sm, const u16* __restrict__ Am, const u16* __restrict__ Alm,
    const u16* __restrict__ Bm, const u16* __restrict__ Blm,
    float* __restrict__ Cf, u16* __restrict__ Ch, u16* __restrict__ Cl,
    int N, int K, int m0, int n0, float oscale) {
  const int tid = threadIdx.x;
  const int w = tid >> 6, lane = tid & 63;
  const int quad = lane >> 4, l16 = lane & 15;
  const int wm = (w >> 1) << 6, wn = (w & 1) << 6;

  // Staging: wave w owns chunks {w, w+8} of the A region and chunk w of B.
  // chunk c (A): q=c>>2, rows (c&3)*64 + lane ; chunk w+8 = same rows, q+2.
  // chunk c (B): q=c>>1, rows (c&1)*64 + lane.
  const size_t aoff = (size_t)(m0 + ((w & 3) << 6) + lane) * K + ((w >> 2) << 3);
  const size_t boff = (size_t)(n0 + ((w & 1) << 6) + lane) * K + ((w >> 1) << 3);
  const int dA0 = w * 512, dA1 = w * 512 + 4096, dB0 = 8192 + w * 512;  // u16 units
  // Fragment read offsets (u16): A: quad*2048 + row*8 ; B: +8192, quad*1024.
  const int aro = quad * 2048 + (wm + l16) * 8;
  const int bro = 8192 + quad * 1024 + (wn + l16) * 8;

  auto STAGE = [&](const u16* MA, const u16* MB, u16* hb, int k0) {
    gload16(MA + aoff + k0, hb + dA0);
    gload16(MA + aoff + k0 + 16, hb + dA1);
    gload16(MB + boff + k0, hb + dB0);
  };

  f32x4 acc[4][4];
#pragma unroll
  for (int i = 0; i < 4; ++i)
#pragma unroll
    for (int n = 0; n < 4; ++n) acc[i][n] = (f32x4){0.f, 0.f, 0.f, 0.f};

  const int NTL = K >> 5;

  // ---- prologue ----
  if (NT == 3) {
    STAGE(Am, Bm, sm, 0);              // h(0)
    STAGE(Alm, Blm, sm + 12288, 0);    // l(0)
    WAITVM(3);                         // h(0) landed, l(0) in flight
  } else {
    STAGE(Am, Bm, sm, 0);
    STAGE(Am, Bm, sm + 12288, 32);
    STAGE(Am, Bm, sm + 24576, 64);
    WAITVM(6);                         // t0 landed, t1/t2 in flight
  }
  SCHED0(); SBAR(); SCHED0();

  if (NT == 3) {
    for (int t = 0; t < NTL; ++t) {
      const int swp = (t & 1) * 24576;
      u16* Hh = sm + swp;              // h-half of tile t
      u16* Hl = Hh + 12288;            // l-half of tile t
      u16* Nh = sm + (24576 - swp);    // h-half of tile t+1 (== h of t-1)
      u16* Nl = Nh + 12288;
      const int k0n = (t + 1) << 5;
      const bool more = (t + 1 < NTL);

      // -------- phase 1: Ah x Bh --------
      f16x8 ahf[4], bhf[4], blf[4], alf[4];
#pragma unroll
      for (int i = 0; i < 4; ++i) ahf[i] = *(const f16x8*)(Hh + aro + i * 128);
#pragma unroll
      for (int n = 0; n < 4; ++n) bhf[n] = *(const f16x8*)(Hh + bro + n * 128);
      if (more) {
        STAGE(Am, Bm, Nh, k0n);        // issue h(t+1)
        WAITVM(3);                     // l(t) landed; h(t+1) stays in flight
      } else {
        WAITVM(0);                     // tail: ensure l(t) landed
      }
      SCHED0(); SBAR();
      WAITLG0(); SCHED0();
      __builtin_amdgcn_s_setprio(1);
      MFMA_BLOCK(ahf, bhf);
      __builtin_amdgcn_s_setprio(0);
      SCHED0(); SBAR(); SCHED0();

      // -------- phase 2: Ah x Bl --------
#pragma unroll
      for (int n = 0; n < 4; ++n) blf[n] = *(const f16x8*)(Hl + bro + n * 128);
      if (more) STAGE(Alm, Blm, Nl, k0n);  // issue l(t+1)
      SCHED0(); SBAR();
      WAITLG0(); SCHED0();
      __builtin_amdgcn_s_setprio(1);
      MFMA_BLOCK(ahf, blf);
      __builtin_amdgcn_s_setprio(0);
      SCHED0(); SBAR(); SCHED0();

      // -------- phase 3: Al x Bh --------
#pragma unroll
      for (int i = 0; i < 4; ++i) alf[i] = *(const f16x8*)(Hl + aro + i * 128);
      WAITVM(3);                       // h(t+1) landed; l(t+1) stays in flight
      SCHED0(); SBAR();
      WAITLG0(); SCHED0();
      __builtin_amdgcn_s_setprio(1);
      MFMA_BLOCK(alf, bhf);
      __builtin_amdgcn_s_setprio(0);
      SCHED0(); SBAR(); SCHED0();
    }
  } else {
    for (int t = 0; t < NTL; ++t) {
      u16* Ht = sm + (t & 3) * 12288;
      f16x8 ahf[4], bhf[4];
#pragma unroll
      for (int i = 0; i < 4; ++i) ahf[i] = *(const f16x8*)(Ht + aro + i * 128);
#pragma unroll
      for (int n = 0; n < 4; ++n) bhf[n] = *(const f16x8*)(Ht + bro + n * 128);
      if (t + 3 < NTL) STAGE(Am, Bm, sm + ((t + 3) & 3) * 12288, (t + 3) << 5);
      const int rem = NTL - 2 - t;     // tiles in flight beyond t+1
      if (rem >= 2) { WAITVM(6); } else if (rem == 1) { WAITVM(3); } else { WAITVM(0); }
      SCHED0(); SBAR();
      WAITLG0(); SCHED0();
      __builtin_amdgcn_s_setprio(1);
      MFMA_BLOCK(ahf, bhf);
      __builtin_amdgcn_s_setprio(0);
      SCHED0(); SBAR(); SCHED0();
    }
  }

  // epilogue: C/D layout row=(lane>>4)*4+r, col=lane&15
#pragma unroll
  for (int i = 0; i < 4; ++i)
#pragma unroll
    for (int n = 0; n < 4; ++n) {
      const int row0 = m0 + wm + i * 16 + quad * 4;
      const int col = n0 + wn + n * 16 + l16;
      if (MODE == 0) {
#pragma unroll
        for (int r = 0; r < 4; ++r) Cf[(size_t)(row0 + r) * N + col] = acc[i][n][r] * oscale;
      } else if (MODE == 1) {
#pragma unroll
        for (int r = 0; r < 4; ++r) {
          float v = acc[i][n][r];
          size_t o = (size_t)(row0 + r) * N + col;
          u16 h = f2h(v);
          Ch[o] = h;
          Cl[o] = f2h(v - h2f(h));
        }
      } else {
        int brow = row0 >> 11, s0 = row0 & 2047;
        int hh = col >> 7, d = col & 127;
        ushort4 pk;
        pk.x = f2h(acc[i][n][0]);
        pk.y = f2h(acc[i][n][1]);
        pk.z = f2h(acc[i][n][2]);
        pk.w = f2h(acc[i][n][3]);
        *(ushort4*)(Ch + ((size_t)(brow * 16 + hh) * 128 + d) * 2048 + s0) = pk;
      }
    }
}

// Fused QKV projection: grid (16, 16, 3); z: Q / K (3-term, pair out), V (1-term, V^T out)
__global__ __launch_bounds__(512, 2) void qkv_kernel(
    const u16* __restrict__ xh, const u16* __restrict__ xl,
    const u16* __restrict__ Wqh, const u16* __restrict__ Wql,
    const u16* __restrict__ Wkh, const u16* __restrict__ Wkl,
    const u16* __restrict__ Wvh,
    u16* qh, u16* ql, u16* kh, u16* kl, u16* vt) {
  __shared__ u16 sm[49152];  // 96 KiB: 4 half-buffers x 24 KiB
  const int m0 = blockIdx.y << 8, n0 = blockIdx.x << 7;
  if (blockIdx.z == 0)
    gemm256<3, 1>(sm, xh, xl, Wqh, Wql, nullptr, qh, ql, DMODEL, DMODEL, m0, n0, 1.f);
  else if (blockIdx.z == 1)
    gemm256<3, 1>(sm, xh, xl, Wkh, Wkl, nullptr, kh, kl, DMODEL, DMODEL, m0, n0, 1.f);
  else
    gemm256<1, 2>(sm, xh, nullptr, Wvh, nullptr, nullptr, vt, nullptr, DMODEL, DMODEL, m0, n0, 1.f);
}

// out = (ch * Woh^T) / 4096  (1-term fp16; dropped terms ~1.5e-4)
__global__ __launch_bounds__(512, 2) void out_kernel(
    const u16* __restrict__ ch, const u16* __restrict__ Woh, float* __restrict__ out) {
  __shared__ u16 sm[49152];
  gemm256<1, 0>(sm, ch, nullptr, Woh, nullptr, out, nullptr, nullptr, DMODEL, DMODEL,
                blockIdx.y << 8, blockIdx.x << 7, 1.f / 4096.f);
}

// RoPE: read fp16 pairs (exact), rotate in f32, write SINGLE fp16.
// q additionally scaled by sqrt(128)/4096 (reference multiplies scores by
// sqrt(128); /4096 compensates the x64 weight scaling on both q and k).
__global__ void rope_f16(u16* __restrict__ qh, const u16* __restrict__ ql,
                         u16* __restrict__ kh, const u16* __restrict__ kl,
                         const float* __restrict__ cosT, const float* __restrict__ sinT) {
  int idx = blockIdx.x * 256 + threadIdx.x;  // [isk][b][s][hh][t]
  int t   = idx & 15;
  int hh  = (idx >> 4) & 15;
  int s   = (idx >> 8) & 2047;
  int b   = (idx >> 19) & 1;
  int isk = (idx >> 20) & 1;
  u16* th = isk ? kh : qh;
  const u16* tl = isk ? kl : ql;
  size_t base = (size_t)(b * 2048 + s) * DMODEL + hh * 128 + t * 4;
  float4 c4 = *(const float4*)&cosT[s * 128 + t * 4];
  float4 s4 = *(const float4*)&sinT[s * 128 + t * 4];
  ushort4 h1 = *(ushort4*)&th[base], h2 = *(ushort4*)&th[base + 64];
  ushort4 lo1 = *(const ushort4*)&tl[base], lo2 = *(const ushort4*)&tl[base + 64];
  float c[4] = {c4.x, c4.y, c4.z, c4.w};
  float sn[4] = {s4.x, s4.y, s4.z, s4.w};
  u16 x1h[4] = {h1.x, h1.y, h1.z, h1.w}, x2h[4] = {h2.x, h2.y, h2.z, h2.w};
  u16 x1l[4] = {lo1.x, lo1.y, lo1.z, lo1.w}, x2l[4] = {lo2.x, lo2.y, lo2.z, lo2.w};
  u16 o1[4], o2[4];
  const float qs = 0.002762135864009951f;  // sqrt(128)/4096
#pragma unroll
  for (int e = 0; e < 4; ++e) {
    float x1 = h2f(x1h[e]) + h2f(x1l[e]);
    float x2 = h2f(x2h[e]) + h2f(x2l[e]);
    float r1 = x1 * c[e] - x2 * sn[e];
    float r2 = x2 * c[e] + x1 * sn[e];
    if (!isk) { r1 *= qs; r2 *= qs; }
    o1[e] = f2h(r1);
    o2[e] = f2h(r2);
  }
  *(ushort4*)&th[base]      = (ushort4){o1[0], o1[1], o1[2], o1[3]};
  *(ushort4*)&th[base + 64] = (ushort4){o2[0], o2[1], o2[2], o2[3]};
}

// Flash attention, causal. 1-term fp16 QK (q pre-scaled), f32 online softmax,
// fp16 P and PV with V^T [b][h][d][s]. BQ=128: 512 thr = 8 waves x 16 q-rows
// sharing K/V tiles (BK=64). P in its OWN per-wave LDS buffer (no aliasing,
// no barrier needed for it: strictly within-wave write->read). 2 barriers/iter.
// Register prefetch of tile kt+1; qt descending; ch = 64*ctx fp16.
__global__ __launch_bounds__(512) void attn_kernel(
    const u16* __restrict__ Qh, const u16* __restrict__ Kh,
    const u16* __restrict__ VT, u16* __restrict__ Ch) {
  const int qt = gridDim.x - 1 - blockIdx.x;  // big blocks first
  const int bh = blockIdx.y;
  const int b = bh >> 4, h = bh & 15;
  const int tid = threadIdx.x;
  const int w = tid >> 6, lane = tid & 63;
  const int quad = lane >> 4, l16 = lane & 15;

  __shared__ u16 sKh[64 * 136];   // K-tile [k][d] pitch 136
  __shared__ u16 sVt[128 * 72];   // V^T tile [d][k], pitch 72
  __shared__ u16 sPb[8 * 1088];   // per-wave P, 16 x 68 each (dedicated)
  u16* sP = &sPb[w * 1088];

  const size_t bhbase = (size_t)b * S_CTX * DMODEL + (size_t)h * 128;
  const size_t vtbase = (size_t)bh * 128 * 2048;

  int kr[2], kc[2], vr[2], vc[2];
#pragma unroll
  for (int j = 0; j < 2; ++j) {
    int c = j * 512 + tid;
    kr[j] = c >> 4; kc[j] = (c & 15) << 3;
    vr[j] = c >> 3; vc[j] = (c & 7) << 3;
  }

  // Q fragments; wave w owns q-rows qt*128 + w*16 + [0,16)
  const int qr0 = qt * 128 + w * 16;
  const size_t qoff = bhbase + (size_t)(qr0 + l16) * DMODEL;
  f16x8 qf[4];
#pragma unroll
  for (int c = 0; c < 4; ++c) qf[c] = *(const f16x8*)(Qh + qoff + c * 32 + quad * 8);

  f32x4 oacc[8];
#pragma unroll
  for (int d = 0; d < 8; ++d) oacc[d] = (f32x4){0.f, 0.f, 0.f, 0.f};
  float m_r[4] = {-INFINITY, -INFINITY, -INFINITY, -INFINITY};
  float l_r[4] = {0.f, 0.f, 0.f, 0.f};

  f16x8 rkh[2], rvt[2];
#pragma unroll
  for (int j = 0; j < 2; ++j) {
    rkh[j] = *(const f16x8*)(Kh + bhbase + (size_t)kr[j] * DMODEL + kc[j]);
    rvt[j] = *(const f16x8*)(VT + vtbase + (size_t)vr[j] * 2048 + vc[j]);
  }

  const int nkt = 2 * qt + 2;
  for (int kt = 0; kt < nkt; ++kt) {
    __syncthreads();  // (1) prev iter QK/PV reads of sKh/sVt done
#pragma unroll
    for (int j = 0; j < 2; ++j) {
      *(f16x8*)&sKh[kr[j] * 136 + kc[j]] = rkh[j];
      *(f16x8*)&sVt[vr[j] * 72 + vc[j]] = rvt[j];
    }
    __syncthreads();  // (2) tiles visible
    if (kt + 1 < nkt) {
#pragma unroll
      for (int j = 0; j < 2; ++j) {
        size_t g = bhbase + (size_t)((kt + 1) * 64 + kr[j]) * DMODEL + kc[j];
        rkh[j] = *(const f16x8*)(Kh + g);
        rvt[j] = *(const f16x8*)(VT + vtbase + (size_t)vr[j] * 2048 + (kt + 1) * 64 + vc[j]);
      }
    }

    const bool active = (kt * 64) <= (qr0 + 15);
    if (active) {
      f32x4 sacc[4];
#pragma unroll
      for (int n = 0; n < 4; ++n) sacc[n] = (f32x4){0.f, 0.f, 0.f, 0.f};
#pragma unroll
      for (int n = 0; n < 4; ++n)
#pragma unroll
        for (int c = 0; c < 4; ++c) {
          f16x8 kf = *(const f16x8*)&sKh[(n * 16 + l16) * 136 + c * 32 + quad * 8];
          sacc[n] = __builtin_amdgcn_mfma_f32_16x16x32_f16(qf[c], kf, sacc[n], 0, 0, 0);
        }

      float pm[4][4];
      float rowmax[4] = {-INFINITY, -INFINITY, -INFINITY, -INFINITY};
#pragma unroll
      for (int n = 0; n < 4; ++n)
#pragma unroll
        for (int r = 0; r < 4; ++r) {
          float sc = sacc[n][r];
          int qi = qr0 + quad * 4 + r;
          int ki = kt * 64 + n * 16 + l16;
          if (ki > qi) sc = -INFINITY;
          pm[n][r] = sc;
          rowmax[r] = fmaxf(rowmax[r], sc);
        }
#pragma unroll
      for (int off = 1; off < 16; off <<= 1)
#pragma unroll
        for (int r = 0; r < 4; ++r)
          rowmax[r] = fmaxf(rowmax[r], __shfl_xor(rowmax[r], off, 64));

      float alphav[4];
#pragma unroll
      for (int r = 0; r < 4; ++r) {
        float mnew = fmaxf(m_r[r], rowmax[r]);
        alphav[r] = __expf(m_r[r] - mnew);
        m_r[r] = mnew;
        l_r[r] *= alphav[r];
      }
      float rowsum[4] = {0.f, 0.f, 0.f, 0.f};
#pragma unroll
      for (int n = 0; n < 4; ++n)
#pragma unroll
        for (int r = 0; r < 4; ++r) {
          float p = __expf(pm[n][r] - m_r[r]);
          pm[n][r] = p;
          rowsum[r] += p;
        }
#pragma unroll
      for (int off = 1; off < 16; off <<= 1)
#pragma unroll
        for (int r = 0; r < 4; ++r) rowsum[r] += __shfl_xor(rowsum[r], off, 64);
#pragma unroll
      for (int r = 0; r < 4; ++r) l_r[r] += rowsum[r];

#pragma unroll
      for (int d = 0; d < 8; ++d)
#pragma unroll
        for (int r = 0; r < 4; ++r) oacc[d][r] *= alphav[r];

      // P (C-layout) -> per-wave dedicated LDS region -> A-layout
#pragma unroll
      for (int n = 0; n < 4; ++n)
#pragma unroll
        for (int r = 0; r < 4; ++r)
          sP[(quad * 4 + r) * 68 + n * 16 + l16] = f2h(pm[n][r]);

      // O += P.V
#pragma unroll
      for (int c = 0; c < 2; ++c) {
        f16x8 pf = *(const f16x8*)&sP[l16 * 68 + c * 32 + quad * 8];
#pragma unroll
        for (int d = 0; d < 8; ++d) {
          f16x8 vf = *(const f16x8*)&sVt[(d * 16 + l16) * 72 + c * 32 + quad * 8];
          oacc[d] = __builtin_amdgcn_mfma_f32_16x16x32_f16(pf, vf, oacc[d], 0, 0, 0);
        }
      }
    }
  }

  float invl[4];
#pragma unroll
  for (int r = 0; r < 4; ++r) invl[r] = 1.f / l_r[r];
#pragma unroll
  for (int d = 0; d < 8; ++d)
#pragma unroll
    for (int r = 0; r < 4; ++r) {
      int row = qr0 + quad * 4 + r;
      Ch[bhbase + (size_t)row * DMODEL + d * 16 + l16] = f2h(oacc[d][r] * invl[r]);
    }
}

extern "C" void kernel_launch(void* const* d_in, const int* in_sizes, int n_in,
                              void* d_out, int out_size, void* d_ws, size_t ws_size,
                              hipStream_t stream) {
  const float* x    = (const float*)d_in[0];
  const float* Wq   = (const float*)d_in[1];
  const float* Wk   = (const float*)d_in[2];
  const float* Wv   = (const float*)d_in[3];
  const float* Wo   = (const float*)d_in[4];
  const float* cosT = (const float*)d_in[5];
  const float* sinT = (const float*)d_in[6];
  float* out = (float*)d_out;

  const size_t NX = 8388608;   // 2*2048*2048
  const size_t NW = 4194304;   // 2048*2048
  u16* p = (u16*)d_ws;
  u16* xh  = p; p += NX;  u16* xl  = p; p += NX;
  u16* Wqh = p; p += NW;  u16* Wql = p; p += NW;
  u16* Wkh = p; p += NW;  u16* Wkl = p; p += NW;
  u16* Wvh = p; p += NW;  u16* Woh = p; p += NW;
  u16* qh  = p; p += NX;  u16* ql  = p; p += NX;
  u16* kh  = p; p += NX;  u16* kl  = p; p += NX;
  u16* vt  = p; p += NX;
  u16* ch  = p; p += NX;
  // ~184 MiB of d_ws

  split_all<<<98304, 256, 0, stream>>>(x, Wq, Wk, Wv, Wo,
                                       xh, xl, Wqh, Wql, Wkh, Wkl, Wvh, Woh);

  // 768 blocks = 3 full waves of 256 CUs at 1 block/CU (96 KiB LDS)
  qkv_kernel<<<dim3(16, 16, 3), 512, 0, stream>>>(xh, xl, Wqh, Wql, Wkh, Wkl, Wvh,
                                                  qh, ql, kh, kl, vt);

  rope_f16<<<8192, 256, 0, stream>>>(qh, ql, kh, kl, cosT, sinT);

  attn_kernel<<<dim3(16, 32), 512, 0, stream>>>(qh, kh, vt, ch);

  out_kernel<<<dim3(16, 16), 512, 0, stream>>>(ch, Woh, out);
}